// Round 7
// baseline (220.699 us; speedup 1.0000x reference)
//
#include <hip/hip_runtime.h>
#include <hip/hip_cooperative_groups.h>

namespace cg = cooperative_groups;

// Problem constants
#define S_   16384
#define T_   16384
#define B_   32
#define NEDGES (S_ * 64)       // 1,048,576
#define GP_  512               // producer blocks, 2048 edges each (32 sources)
#define EPG  2048              // edges per producer block
#define NBKT 512               // buckets of 32 targets
#define TPB  32                // targets per bucket
#define CAPT 128               // per-target slots: mean 64, global max ~100
#define OVF_CAP 64             // overflow records (expected ~0)

// weight = clip(att,0,1) * 0.9^delay, delay in [0,6). Exact bit-product.
__device__ __forceinline__ float edge_weight(float a, int d) {
  float w = fminf(fmaxf(a, 0.0f), 1.0f);
  float r = (d & 1) ? 0.9f : 1.0f;
  r = (d & 2) ? r * 0.81f   : r;
  r = (d & 4) ? r * 0.6561f : r;
  return w * r;
}

// ---------------------------------------------------------------------------
// Shared-memory union: produce phase and consume phase reuse one allocation.
struct ProdSh {
  float tile[32][33];                   // 4.2 KB spike transpose tile
  int2  buf[EPG];                       // 16 KB bucket-sorted records
  int   cnt[NBKT], cur[NBKT], sofs[NBKT]; // 6 KB
  int   wtot[8];
};
struct ConsSh {
  int2  srt[TPB * CAPT];                // 32 KB, target t owns [t*CAPT,...)
  float otile[TPB][33];                 // 4.2 KB
  unsigned sse[GP_];                    // 2 KB
  int   cur32[TPB];
  int2  ovf[OVF_CAP];
  int   ovfn;
};
union SMem { ProdSh p; ConsSh c; };     // ~39.7 KB -> 2 blocks/CU

// ---------------------------------------------------------------------------
// Produce phase: block g transposes 32 sources of spikes + counting-sorts its
// 2048 edges into 512 buckets in LDS + one contiguous 16 KB flush.
// rec[g][i]: records {meta = tl<<14 | src, w_bits} grouped by bucket;
// ofse[g][k] = end<<16 | start.
__device__ __forceinline__ void produce_phase(
    SMem& smu, const int g, const int tid,
    const float* __restrict__ spikes, const float* __restrict__ att,
    const int* __restrict__ tgt, const int* __restrict__ del,
    float* __restrict__ spikesT, int2* __restrict__ rec,
    unsigned int* __restrict__ ofse) {
  ProdSh& sm = smu.p;
  if (tid < NBKT) sm.cnt[tid] = 0;

  const int s0 = g * 32;
  {
    const int x = tid & 31, y = tid >> 5;       // y 0..15
    sm.tile[x][y]      = spikes[(size_t)y        * S_ + s0 + x];
    sm.tile[x][y + 16] = spikes[(size_t)(y + 16) * S_ + s0 + x];
  }

  // my 4 edges, kept in registers
  const int e4  = g * 512 + tid;
  int4   t = reinterpret_cast<const int4*>(tgt)[e4];
  float4 a = reinterpret_cast<const float4*>(att)[e4];
  int4   d = reinterpret_cast<const int4*>(del)[e4];
  const int src = (e4 * 4) >> 6;                // 4 consecutive edges: 1 source

  __syncthreads();                              // cnt init + tile visible

  // transpose write
  {
    const int b = tid & 31, j = tid >> 5;       // j 0..15
    spikesT[(size_t)(s0 + j)      * 32 + b] = sm.tile[j][b];
    spikesT[(size_t)(s0 + j + 16) * 32 + b] = sm.tile[j + 16][b];
  }

  // histogram
  const int bk0 = t.x >> 5, bk1 = t.y >> 5, bk2 = t.z >> 5, bk3 = t.w >> 5;
  __hip_atomic_fetch_add(&sm.cnt[bk0], 1, __ATOMIC_RELAXED, __HIP_MEMORY_SCOPE_WORKGROUP);
  __hip_atomic_fetch_add(&sm.cnt[bk1], 1, __ATOMIC_RELAXED, __HIP_MEMORY_SCOPE_WORKGROUP);
  __hip_atomic_fetch_add(&sm.cnt[bk2], 1, __ATOMIC_RELAXED, __HIP_MEMORY_SCOPE_WORKGROUP);
  __hip_atomic_fetch_add(&sm.cnt[bk3], 1, __ATOMIC_RELAXED, __HIP_MEMORY_SCOPE_WORKGROUP);
  __syncthreads();

  // exclusive scan of 512 bins: 8 waves shuffle-scan 64 each + combine
  int v = sm.cnt[tid];
  int incl = v;
#pragma unroll
  for (int off = 1; off < 64; off <<= 1) {
    int u = __shfl_up(incl, off);
    if ((tid & 63) >= off) incl += u;
  }
  if ((tid & 63) == 63) sm.wtot[tid >> 6] = incl;
  __syncthreads();
  {
    int base = 0;
    const int wv = tid >> 6;
    for (int i = 0; i < wv; ++i) base += sm.wtot[i];
    const int start = base + incl - v;
    sm.sofs[tid] = start;
    sm.cur[tid]  = start;
  }
  __syncthreads();

  // weight + place at bucket cursor (exact, no overflow possible)
#define PUT(BK, TL, AV, DV)                                                   \
  {                                                                           \
    int p = __hip_atomic_fetch_add(&sm.cur[BK], 1, __ATOMIC_RELAXED,          \
                                   __HIP_MEMORY_SCOPE_WORKGROUP);             \
    sm.buf[p] = make_int2(((TL) << 14) | src,                                 \
                          __float_as_int(edge_weight((AV), (DV))));           \
  }
  PUT(bk0, t.x & 31, a.x, d.x)
  PUT(bk1, t.y & 31, a.y, d.y)
  PUT(bk2, t.z & 31, a.z, d.z)
  PUT(bk3, t.w & 31, a.w, d.w)
#undef PUT
  __syncthreads();

  // flush: one contiguous 16 KB stream (int4 x2 per thread) + ofse
  const int4* sbuf4 = reinterpret_cast<const int4*>(sm.buf);
  int4* recO = reinterpret_cast<int4*>(rec) + (size_t)g * (EPG / 2);
  recO[tid]       = sbuf4[tid];
  recO[tid + 512] = sbuf4[tid + 512];
  ofse[(size_t)g * NBKT + tid] =
      ((unsigned)sm.cur[tid] << 16) | (unsigned)sm.sofs[tid];
}

// ---------------------------------------------------------------------------
// Consume phase: bucket k gathers its 512 slices (4 lanes/slice, 128 slices
// concurrent), places records directly in fixed 128-slot per-target slices,
// then register-gather + coalesced out write. No fine sort (v6 structure).
__device__ __forceinline__ void consume_phase(
    SMem& smu, const int k, const int tid,
    const int2* __restrict__ rec, const unsigned int* __restrict__ ofse,
    const float* __restrict__ spikesT, float* __restrict__ out) {
  ConsSh& sm = smu.c;
  const int b  = tid & 31;
  const int hw = tid >> 5;              // 0..15

  if (tid < TPB) sm.cur32[tid] = tid * CAPT;
  if (tid == 0)  sm.ovfn = 0;
  sm.sse[tid] = ofse[(size_t)tid * NBKT + k];
  __syncthreads();

  // pass 1: 4 lanes per slice (avg n~4), 128 slices concurrent, 4 iters
  {
    const int grp = tid >> 2;           // 0..127
    const int l4  = tid & 3;
    for (int it = 0; it < 4; ++it) {
      const int g = grp + it * 128;
      const unsigned u = sm.sse[g];
      const int st = (int)(u & 0xFFFF);
      const int n  = (int)(u >> 16) - st;
      const int2* slice = rec + (size_t)g * EPG + st;
      for (int j = l4; j < n; j += 4) {
        int2 r = slice[j];
        const int tl = (r.x >> 14) & 31;
        int p = __hip_atomic_fetch_add(&sm.cur32[tl], 1, __ATOMIC_RELAXED,
                                       __HIP_MEMORY_SCOPE_WORKGROUP);
        if (p < (tl + 1) * CAPT) {
          sm.srt[p] = r;
        } else {
          int q = __hip_atomic_fetch_add(&sm.ovfn, 1, __ATOMIC_RELAXED,
                                         __HIP_MEMORY_SCOPE_WORKGROUP);
          if (q < OVF_CAP) sm.ovf[q] = r;
        }
      }
    }
  }
  __syncthreads();

  // gather: half-wave hw owns targets hw (acc0) and hw+16 (acc1); lane=batch.
  float acc0 = 0.f, acc1 = 0.f;
  int e0 = hw * CAPT;
  int e1 = (hw + 16) * CAPT;
  const int e0e = min(sm.cur32[hw],      (hw + 1)  * CAPT);
  const int e1e = min(sm.cur32[hw + 16], (hw + 17) * CAPT);

  for (; e0 + 4 <= e0e && e1 + 4 <= e1e; e0 += 4, e1 += 4) {
    int2 r0 = sm.srt[e0], r1 = sm.srt[e0 + 1], r2 = sm.srt[e0 + 2], r3 = sm.srt[e0 + 3];
    int2 q0 = sm.srt[e1], q1 = sm.srt[e1 + 1], q2 = sm.srt[e1 + 2], q3 = sm.srt[e1 + 3];
    float s0 = spikesT[(size_t)(r0.x & 0x3FFF) * 32 + b];
    float s1 = spikesT[(size_t)(r1.x & 0x3FFF) * 32 + b];
    float s2 = spikesT[(size_t)(r2.x & 0x3FFF) * 32 + b];
    float s3 = spikesT[(size_t)(r3.x & 0x3FFF) * 32 + b];
    float u0 = spikesT[(size_t)(q0.x & 0x3FFF) * 32 + b];
    float u1 = spikesT[(size_t)(q1.x & 0x3FFF) * 32 + b];
    float u2 = spikesT[(size_t)(q2.x & 0x3FFF) * 32 + b];
    float u3 = spikesT[(size_t)(q3.x & 0x3FFF) * 32 + b];
    acc0 = fmaf(__int_as_float(r0.y), s0, acc0);
    acc0 = fmaf(__int_as_float(r1.y), s1, acc0);
    acc0 = fmaf(__int_as_float(r2.y), s2, acc0);
    acc0 = fmaf(__int_as_float(r3.y), s3, acc0);
    acc1 = fmaf(__int_as_float(q0.y), u0, acc1);
    acc1 = fmaf(__int_as_float(q1.y), u1, acc1);
    acc1 = fmaf(__int_as_float(q2.y), u2, acc1);
    acc1 = fmaf(__int_as_float(q3.y), u3, acc1);
  }
  for (; e0 + 4 <= e0e; e0 += 4) {
    int2 r0 = sm.srt[e0], r1 = sm.srt[e0 + 1], r2 = sm.srt[e0 + 2], r3 = sm.srt[e0 + 3];
    float s0 = spikesT[(size_t)(r0.x & 0x3FFF) * 32 + b];
    float s1 = spikesT[(size_t)(r1.x & 0x3FFF) * 32 + b];
    float s2 = spikesT[(size_t)(r2.x & 0x3FFF) * 32 + b];
    float s3 = spikesT[(size_t)(r3.x & 0x3FFF) * 32 + b];
    acc0 = fmaf(__int_as_float(r0.y), s0, acc0);
    acc0 = fmaf(__int_as_float(r1.y), s1, acc0);
    acc0 = fmaf(__int_as_float(r2.y), s2, acc0);
    acc0 = fmaf(__int_as_float(r3.y), s3, acc0);
  }
  for (; e0 < e0e; ++e0) {
    int2 r = sm.srt[e0];
    acc0 = fmaf(__int_as_float(r.y), spikesT[(size_t)(r.x & 0x3FFF) * 32 + b], acc0);
  }
  for (; e1 + 4 <= e1e; e1 += 4) {
    int2 q0 = sm.srt[e1], q1 = sm.srt[e1 + 1], q2 = sm.srt[e1 + 2], q3 = sm.srt[e1 + 3];
    float u0 = spikesT[(size_t)(q0.x & 0x3FFF) * 32 + b];
    float u1 = spikesT[(size_t)(q1.x & 0x3FFF) * 32 + b];
    float u2 = spikesT[(size_t)(q2.x & 0x3FFF) * 32 + b];
    float u3 = spikesT[(size_t)(q3.x & 0x3FFF) * 32 + b];
    acc1 = fmaf(__int_as_float(q0.y), u0, acc1);
    acc1 = fmaf(__int_as_float(q1.y), u1, acc1);
    acc1 = fmaf(__int_as_float(q2.y), u2, acc1);
    acc1 = fmaf(__int_as_float(q3.y), u3, acc1);
  }
  for (; e1 < e1e; ++e1) {
    int2 q = sm.srt[e1];
    acc1 = fmaf(__int_as_float(q.y), spikesT[(size_t)(q.x & 0x3FFF) * 32 + b], acc1);
  }

  // overflow drain (expected empty)
  const int no = min(sm.ovfn, OVF_CAP);
  for (int j = 0; j < no; ++j) {
    int2 r = sm.ovf[j];
    const int tl = (r.x >> 14) & 31;
    float s = spikesT[(size_t)(r.x & 0x3FFF) * 32 + b];
    float w = __int_as_float(r.y);
    if (tl == hw)      acc0 = fmaf(w, s, acc0);
    if (tl == hw + 16) acc1 = fmaf(w, s, acc1);
  }

  // transpose 32x32 tile, write out coalesced
  sm.otile[hw][b]      = acc0;
  sm.otile[hw + 16][b] = acc1;
  __syncthreads();
  const int bb = tid >> 4;              // batch 0..31
  const int cc = (tid & 15) * 2;        // target pair
  float2 o2 = make_float2(sm.otile[cc][bb], sm.otile[cc + 1][bb]);
  *reinterpret_cast<float2*>(&out[(size_t)bb * T_ + k * 32 + cc]) = o2;
}

// ---------------------------------------------------------------------------
// Fused cooperative kernel: produce -> grid.sync -> consume. Grid = 512
// blocks x 512 threads = 2 blocks/CU (LDS 39.7KB, launch_bounds caps VGPR).
__global__ __launch_bounds__(512, 4) void fused(
    const float* __restrict__ spikes, const float* __restrict__ att,
    const int* __restrict__ tgt, const int* __restrict__ del,
    float* __restrict__ spikesT, int2* __restrict__ rec,
    unsigned int* __restrict__ ofse, float* __restrict__ out) {
  __shared__ SMem sm;
  produce_phase(sm, blockIdx.x, threadIdx.x, spikes, att, tgt, del,
                spikesT, rec, ofse);
  __threadfence();
  cg::this_grid().sync();
  consume_phase(sm, blockIdx.x, threadIdx.x, rec, ofse, spikesT, out);
}

// Fallback: same phases as two ordinary kernels.
__global__ __launch_bounds__(512) void produce_k(
    const float* __restrict__ spikes, const float* __restrict__ att,
    const int* __restrict__ tgt, const int* __restrict__ del,
    float* __restrict__ spikesT, int2* __restrict__ rec,
    unsigned int* __restrict__ ofse) {
  __shared__ SMem sm;
  produce_phase(sm, blockIdx.x, threadIdx.x, spikes, att, tgt, del,
                spikesT, rec, ofse);
}
__global__ __launch_bounds__(512) void consume_k(
    const int2* __restrict__ rec, const unsigned int* __restrict__ ofse,
    const float* __restrict__ spikesT, float* __restrict__ out) {
  __shared__ SMem sm;
  consume_phase(sm, blockIdx.x, threadIdx.x, rec, ofse, spikesT, out);
}

// ---------------------------------------------------------------------------
__global__ void zero_floats(float* __restrict__ p, int n) {
  int i = blockIdx.x * blockDim.x + threadIdx.x;
  if (i < n) p[i] = 0.0f;
}

// Emergency fallback (tiny ws): direct global atomics, weights inline.
__global__ void naive_kernel(const float* __restrict__ spikes,
                             const float* __restrict__ att,
                             const int*   __restrict__ tgt,
                             const int*   __restrict__ del,
                             float*       __restrict__ out) {
  int i = blockIdx.x * blockDim.x + threadIdx.x;
  if (i >= NEDGES) return;
  int   s = i >> 6;
  int   t = tgt[i];
  float w = edge_weight(att[i], del[i]);
  for (int b = 0; b < B_; ++b)
    unsafeAtomicAdd(&out[(size_t)b * T_ + t], w * spikes[(size_t)b * S_ + s]);
}

// ---------------------------------------------------------------------------
extern "C" void kernel_launch(void* const* d_in, const int* in_sizes, int n_in,
                              void* d_out, int out_size, void* d_ws, size_t ws_size,
                              hipStream_t stream) {
  const float* spikes = (const float*)d_in[0];
  const float* att    = (const float*)d_in[1];
  const int*   tgt    = (const int*)d_in[2];
  const int*   del    = (const int*)d_in[3];
  float*       out    = (float*)d_out;

  const size_t spikesT_bytes = (size_t)S_ * B_ * sizeof(float);         // 2 MB
  const size_t rec_bytes     = (size_t)NEDGES * sizeof(int2);           // 8 MB
  const size_t ofse_bytes    = (size_t)GP_ * NBKT * sizeof(unsigned);   // 1 MB
  const size_t need = spikesT_bytes + rec_bytes + ofse_bytes + 64;

  if (ws_size < need) {
    zero_floats<<<(B_ * T_ + 255) / 256, 256, 0, stream>>>(out, B_ * T_);
    naive_kernel<<<(NEDGES + 255) / 256, 256, 0, stream>>>(spikes, att, tgt, del, out);
    return;
  }

  char* p = (char*)d_ws;
  float*        spikesT = (float*)p;        p += spikesT_bytes;
  int2*         rec     = (int2*)p;         p += rec_bytes;
  unsigned int* ofse    = (unsigned int*)p;

  // Gate cooperative launch on actual co-residency (host queries only; no
  // stream ops, graph-capture-safe). Cached across calls.
  static int coop_ok = -1;
  if (coop_ok < 0) {
    int dev = 0;
    hipGetDevice(&dev);
    hipDeviceProp_t prop;
    hipGetDeviceProperties(&prop, dev);
    int nb = 0;
    hipOccupancyMaxActiveBlocksPerMultiprocessor(&nb, fused, 512, 0);
    coop_ok = (prop.cooperativeLaunch && nb * prop.multiProcessorCount >= GP_) ? 1 : 0;
  }

  if (coop_ok) {
    void* args[] = {(void*)&spikes, (void*)&att, (void*)&tgt, (void*)&del,
                    (void*)&spikesT, (void*)&rec, (void*)&ofse, (void*)&out};
    hipError_t rc = hipLaunchCooperativeKernel((const void*)fused, dim3(GP_),
                                               dim3(512), args, 0, stream);
    if (rc == hipSuccess) return;
    coop_ok = 0;  // fall through to two-kernel path
  }

  produce_k<<<GP_, 512, 0, stream>>>(spikes, att, tgt, del, spikesT, rec, ofse);
  consume_k<<<NBKT, 512, 0, stream>>>(rec, ofse, spikesT, out);
}

// Round 8
// 87.634 us; speedup vs baseline: 2.5184x; 2.5184x over previous
//
#include <hip/hip_runtime.h>

// Problem constants
#define S_   16384
#define T_   16384
#define B_   32
#define NEDGES (S_ * 64)       // 1,048,576
#define GP_  256               // producer blocks, 4096 edges each
#define EPG  4096              // edges per producer block
#define NBKT 512               // buckets of 32 targets
#define TPB  32                // targets per bucket
#define CAPT 128               // per-target slots: mean 64, global max ~100
#define OVF_CAP 64             // overflow records (expected ~0)

// weight = clip(att,0,1) * 0.9^delay, delay in [0,6). Exact bit-product.
__device__ __forceinline__ float edge_weight(float a, int d) {
  float w = fminf(fmaxf(a, 0.0f), 1.0f);
  float r = (d & 1) ? 0.9f : 1.0f;
  r = (d & 2) ? r * 0.81f   : r;
  r = (d & 4) ? r * 0.6561f : r;
  return w * r;
}

// ---------------------------------------------------------------------------
// K1: transpose 64 sources of spikes + LDS counting-sort of 4096 edges by
// bucket + ONE contiguous 32 KB flush. rec[g][i]: records
// {meta = tl<<14 | src, w_bits} grouped by bucket.
// ofse layout is TRANSPOSED: ofse[k*GP_ + g] = end<<16 | start, so consume
// block k reads a contiguous 1KB burst instead of 256 stride-2KB gathers
// (v6 counters: ~8MB of line over-fetch from the strided gather).
__global__ __launch_bounds__(1024) void produce(
    const float* __restrict__ spikes,
    const float* __restrict__ att,
    const int*   __restrict__ tgt,
    const int*   __restrict__ del,
    float*        __restrict__ spikesT,
    int2*         __restrict__ rec,
    unsigned int* __restrict__ ofse) {
  __shared__ float tile[64][33];        // 8.4 KB
  __shared__ int4  sbuf4[EPG / 2];      // 32 KB: 4096 int2 records
  __shared__ int   cnt5[NBKT], cur5[NBKT], sofs5[NBKT];
  __shared__ int   wtot[8];
  int2* buf = (int2*)sbuf4;

  const int g   = blockIdx.x;
  const int tid = threadIdx.x;
  if (tid < NBKT) cnt5[tid] = 0;

  // -- transpose sources [g*64, g*64+64): load half
  const int s0 = g * 64;
  {
    const int x = tid & 63, y = tid >> 6;       // y 0..15
    tile[x][y]      = spikes[(size_t)y        * S_ + s0 + x];
    tile[x][y + 16] = spikes[(size_t)(y + 16) * S_ + s0 + x];
  }

  // -- load my 4 edges (kept in registers across all phases)
  const int e4  = g * 1024 + tid;
  int4   t = reinterpret_cast<const int4*>(tgt)[e4];
  float4 a = reinterpret_cast<const float4*>(att)[e4];
  int4   d = reinterpret_cast<const int4*>(del)[e4];
  const int src = (e4 * 4) >> 6;                // 4 consecutive edges: 1 source

  __syncthreads();                              // cnt5 init + tile visible

  // -- transpose write
  {
    const int b = tid & 31, j = tid >> 5;       // j 0..31
    spikesT[(size_t)(s0 + j)      * 32 + b] = tile[j][b];
    spikesT[(size_t)(s0 + j + 32) * 32 + b] = tile[j + 32][b];
  }

  // -- pass 1: bucket histogram (ds_add, no return needed)
  const int bk0 = t.x >> 5, bk1 = t.y >> 5, bk2 = t.z >> 5, bk3 = t.w >> 5;
  __hip_atomic_fetch_add(&cnt5[bk0], 1, __ATOMIC_RELAXED, __HIP_MEMORY_SCOPE_WORKGROUP);
  __hip_atomic_fetch_add(&cnt5[bk1], 1, __ATOMIC_RELAXED, __HIP_MEMORY_SCOPE_WORKGROUP);
  __hip_atomic_fetch_add(&cnt5[bk2], 1, __ATOMIC_RELAXED, __HIP_MEMORY_SCOPE_WORKGROUP);
  __hip_atomic_fetch_add(&cnt5[bk3], 1, __ATOMIC_RELAXED, __HIP_MEMORY_SCOPE_WORKGROUP);
  __syncthreads();

  // -- exclusive scan of 512 bins: waves 0..7 shuffle-scan 64 each + combine
  int v = 0, incl = 0;
  if (tid < NBKT) {
    v = cnt5[tid];
    incl = v;
#pragma unroll
    for (int off = 1; off < 64; off <<= 1) {
      int u = __shfl_up(incl, off);
      if ((tid & 63) >= off) incl += u;
    }
    if ((tid & 63) == 63) wtot[tid >> 6] = incl;
  }
  __syncthreads();
  if (tid < NBKT) {
    int base = 0;
    const int wv = tid >> 6;
    for (int i = 0; i < wv; ++i) base += wtot[i];
    const int start = base + incl - v;
    sofs5[tid] = start;
    cur5[tid]  = start;
  }
  __syncthreads();

  // -- pass 2: weight + place into LDS at bucket cursor (exact, no overflow)
#define PUT(BK, TL, AV, DV)                                                   \
  {                                                                           \
    int p = __hip_atomic_fetch_add(&cur5[BK], 1, __ATOMIC_RELAXED,            \
                                   __HIP_MEMORY_SCOPE_WORKGROUP);             \
    buf[p] = make_int2(((TL) << 14) | src,                                    \
                       __float_as_int(edge_weight((AV), (DV))));              \
  }
  PUT(bk0, t.x & 31, a.x, d.x)
  PUT(bk1, t.y & 31, a.y, d.y)
  PUT(bk2, t.z & 31, a.z, d.z)
  PUT(bk3, t.w & 31, a.w, d.w)
#undef PUT
  __syncthreads();

  // -- flush: one contiguous 32 KB stream of full lines (int4 x2 per thread)
  int4* recO = reinterpret_cast<int4*>(rec) + (size_t)g * (EPG / 2);
  recO[tid]        = sbuf4[tid];
  recO[tid + 1024] = sbuf4[tid + 1024];
  if (tid < NBKT)
    ofse[(size_t)tid * GP_ + g] =          // transposed: column g, 4B stores
        ((unsigned)cur5[tid] << 16) | (unsigned)sofs5[tid];
}

// ---------------------------------------------------------------------------
// K2 (v8 = v6 + contiguous ofse read): fixed 128-slot per-target LDS slices,
// direct placement in pass 1 (no fine sort), interleaved register gather.
__global__ __launch_bounds__(512) void consume(
    const int2*  __restrict__ rec,
    const unsigned int* __restrict__ ofse,
    const float* __restrict__ spikesT,
    float* __restrict__ out) {
  __shared__ int2  srt[TPB * CAPT];     // 32 KB, target t owns [t*CAPT, ...)
  __shared__ float otile[TPB][33];      // 4.2 KB
  __shared__ unsigned sse[GP_];         // 1 KB
  __shared__ int   cur32[TPB];
  __shared__ int2  ovf[OVF_CAP];
  __shared__ int   ovfn;

  const int k   = blockIdx.x;
  const int tid = threadIdx.x;
  const int b   = tid & 31;
  const int hw  = tid >> 5;             // 0..15

  if (tid < TPB) cur32[tid] = tid * CAPT;
  if (tid == 0)  ovfn = 0;
  if (tid < GP_) sse[tid] = ofse[(size_t)k * GP_ + tid];   // contiguous 1KB
  __syncthreads();

  // pass 1: 8 lanes per slice, 64 slices concurrent; direct placement.
  {
    const int grp = tid >> 3;           // 0..63
    const int l8  = tid & 7;
    for (int it = 0; it < 4; ++it) {
      const int g = grp + it * 64;
      const unsigned u = sse[g];
      const int st = (int)(u & 0xFFFF);
      const int n  = (int)(u >> 16) - st;
      const int2* slice = rec + (size_t)g * EPG + st;
      for (int j = l8; j < n; j += 8) {
        int2 r = slice[j];
        const int tl = (r.x >> 14) & 31;
        int p = __hip_atomic_fetch_add(&cur32[tl], 1, __ATOMIC_RELAXED,
                                       __HIP_MEMORY_SCOPE_WORKGROUP);
        if (p < (tl + 1) * CAPT) {
          srt[p] = r;
        } else {
          int q = __hip_atomic_fetch_add(&ovfn, 1, __ATOMIC_RELAXED,
                                         __HIP_MEMORY_SCOPE_WORKGROUP);
          if (q < OVF_CAP) ovf[q] = r;
        }
      }
    }
  }
  __syncthreads();

  // gather: half-wave hw owns targets hw (acc0) and hw+16 (acc1); lane=batch.
  // Interleaved 4+4 so 8 srt reads + 8 spikesT loads are outstanding.
  float acc0 = 0.f, acc1 = 0.f;
  int e0 = hw * CAPT;
  int e1 = (hw + 16) * CAPT;
  const int e0e = min(cur32[hw],      (hw + 1)  * CAPT);
  const int e1e = min(cur32[hw + 16], (hw + 17) * CAPT);

  for (; e0 + 4 <= e0e && e1 + 4 <= e1e; e0 += 4, e1 += 4) {
    int2 r0 = srt[e0], r1 = srt[e0 + 1], r2 = srt[e0 + 2], r3 = srt[e0 + 3];
    int2 q0 = srt[e1], q1 = srt[e1 + 1], q2 = srt[e1 + 2], q3 = srt[e1 + 3];
    float s0 = spikesT[(size_t)(r0.x & 0x3FFF) * 32 + b];
    float s1 = spikesT[(size_t)(r1.x & 0x3FFF) * 32 + b];
    float s2 = spikesT[(size_t)(r2.x & 0x3FFF) * 32 + b];
    float s3 = spikesT[(size_t)(r3.x & 0x3FFF) * 32 + b];
    float u0 = spikesT[(size_t)(q0.x & 0x3FFF) * 32 + b];
    float u1 = spikesT[(size_t)(q1.x & 0x3FFF) * 32 + b];
    float u2 = spikesT[(size_t)(q2.x & 0x3FFF) * 32 + b];
    float u3 = spikesT[(size_t)(q3.x & 0x3FFF) * 32 + b];
    acc0 = fmaf(__int_as_float(r0.y), s0, acc0);
    acc0 = fmaf(__int_as_float(r1.y), s1, acc0);
    acc0 = fmaf(__int_as_float(r2.y), s2, acc0);
    acc0 = fmaf(__int_as_float(r3.y), s3, acc0);
    acc1 = fmaf(__int_as_float(q0.y), u0, acc1);
    acc1 = fmaf(__int_as_float(q1.y), u1, acc1);
    acc1 = fmaf(__int_as_float(q2.y), u2, acc1);
    acc1 = fmaf(__int_as_float(q3.y), u3, acc1);
  }
  // drain target A
  for (; e0 + 4 <= e0e; e0 += 4) {
    int2 r0 = srt[e0], r1 = srt[e0 + 1], r2 = srt[e0 + 2], r3 = srt[e0 + 3];
    float s0 = spikesT[(size_t)(r0.x & 0x3FFF) * 32 + b];
    float s1 = spikesT[(size_t)(r1.x & 0x3FFF) * 32 + b];
    float s2 = spikesT[(size_t)(r2.x & 0x3FFF) * 32 + b];
    float s3 = spikesT[(size_t)(r3.x & 0x3FFF) * 32 + b];
    acc0 = fmaf(__int_as_float(r0.y), s0, acc0);
    acc0 = fmaf(__int_as_float(r1.y), s1, acc0);
    acc0 = fmaf(__int_as_float(r2.y), s2, acc0);
    acc0 = fmaf(__int_as_float(r3.y), s3, acc0);
  }
  for (; e0 < e0e; ++e0) {
    int2 r = srt[e0];
    acc0 = fmaf(__int_as_float(r.y), spikesT[(size_t)(r.x & 0x3FFF) * 32 + b], acc0);
  }
  // drain target B
  for (; e1 + 4 <= e1e; e1 += 4) {
    int2 q0 = srt[e1], q1 = srt[e1 + 1], q2 = srt[e1 + 2], q3 = srt[e1 + 3];
    float u0 = spikesT[(size_t)(q0.x & 0x3FFF) * 32 + b];
    float u1 = spikesT[(size_t)(q1.x & 0x3FFF) * 32 + b];
    float u2 = spikesT[(size_t)(q2.x & 0x3FFF) * 32 + b];
    float u3 = spikesT[(size_t)(q3.x & 0x3FFF) * 32 + b];
    acc1 = fmaf(__int_as_float(q0.y), u0, acc1);
    acc1 = fmaf(__int_as_float(q1.y), u1, acc1);
    acc1 = fmaf(__int_as_float(q2.y), u2, acc1);
    acc1 = fmaf(__int_as_float(q3.y), u3, acc1);
  }
  for (; e1 < e1e; ++e1) {
    int2 q = srt[e1];
    acc1 = fmaf(__int_as_float(q.y), spikesT[(size_t)(q.x & 0x3FFF) * 32 + b], acc1);
  }

  // overflow drain (expected empty; correctness net for slice > CAPT)
  const int no = min(ovfn, OVF_CAP);
  for (int j = 0; j < no; ++j) {
    int2 r = ovf[j];
    const int tl = (r.x >> 14) & 31;
    float s = spikesT[(size_t)(r.x & 0x3FFF) * 32 + b];
    float w = __int_as_float(r.y);
    if (tl == hw)      acc0 = fmaf(w, s, acc0);
    if (tl == hw + 16) acc1 = fmaf(w, s, acc1);
  }

  // transpose 32x32 tile and write out coalesced
  otile[hw][b]      = acc0;
  otile[hw + 16][b] = acc1;
  __syncthreads();
  const int bb = tid >> 4;              // batch 0..31
  const int cc = (tid & 15) * 2;        // target pair
  float2 o2 = make_float2(otile[cc][bb], otile[cc + 1][bb]);
  *reinterpret_cast<float2*>(&out[(size_t)bb * T_ + k * 32 + cc]) = o2;
}

// ---------------------------------------------------------------------------
__global__ void zero_floats(float* __restrict__ p, int n) {
  int i = blockIdx.x * blockDim.x + threadIdx.x;
  if (i < n) p[i] = 0.0f;
}

// Emergency fallback (tiny ws): direct global atomics, weights inline.
__global__ void naive_kernel(const float* __restrict__ spikes,
                             const float* __restrict__ att,
                             const int*   __restrict__ tgt,
                             const int*   __restrict__ del,
                             float*       __restrict__ out) {
  int i = blockIdx.x * blockDim.x + threadIdx.x;
  if (i >= NEDGES) return;
  int   s = i >> 6;
  int   t = tgt[i];
  float w = edge_weight(att[i], del[i]);
  for (int b = 0; b < B_; ++b)
    unsafeAtomicAdd(&out[(size_t)b * T_ + t], w * spikes[(size_t)b * S_ + s]);
}

// ---------------------------------------------------------------------------
extern "C" void kernel_launch(void* const* d_in, const int* in_sizes, int n_in,
                              void* d_out, int out_size, void* d_ws, size_t ws_size,
                              hipStream_t stream) {
  const float* spikes = (const float*)d_in[0];
  const float* att    = (const float*)d_in[1];
  const int*   tgt    = (const int*)d_in[2];
  const int*   del    = (const int*)d_in[3];
  float*       out    = (float*)d_out;

  const size_t spikesT_bytes = (size_t)S_ * B_ * sizeof(float);         // 2 MB
  const size_t rec_bytes     = (size_t)NEDGES * sizeof(int2);           // 8 MB
  const size_t ofse_bytes    = (size_t)GP_ * NBKT * sizeof(unsigned);   // 512 KB
  const size_t need = spikesT_bytes + rec_bytes + ofse_bytes + 64;

  if (ws_size < need) {
    zero_floats<<<(B_ * T_ + 255) / 256, 256, 0, stream>>>(out, B_ * T_);
    naive_kernel<<<(NEDGES + 255) / 256, 256, 0, stream>>>(spikes, att, tgt, del, out);
    return;
  }

  char* p = (char*)d_ws;
  float*        spikesT = (float*)p;        p += spikesT_bytes;
  int2*         rec     = (int2*)p;         p += rec_bytes;
  unsigned int* ofse    = (unsigned int*)p;

  produce<<<GP_, 1024, 0, stream>>>(spikes, att, tgt, del, spikesT, rec, ofse);
  consume<<<NBKT, 512, 0, stream>>>(rec, ofse, spikesT, out);
}